// Round 1
// baseline (183.305 us; speedup 1.0000x reference)
//
#include <hip/hip_runtime.h>
#include <hip/hip_bf16.h>

typedef __attribute__((ext_vector_type(8))) short bf16x8;
typedef __attribute__((ext_vector_type(4))) float f32x4;

static __device__ __forceinline__ uint bf16rne(float f) {
    uint u = __float_as_uint(f);
    return (u + 0x7fffu + ((u >> 16) & 1u)) >> 16;
}

// K1: style_plus1[b][c] = 1 + affine_b[c] + dot(w[b,:], affine_w[c,:])
__global__ void k_style(const float* __restrict__ w, const float* __restrict__ aw,
                        const float* __restrict__ ab, float* __restrict__ style) {
    int idx = blockIdx.x * 4 + (threadIdx.x >> 6);   // (b,c) pair, 4096 total
    int lane = threadIdx.x & 63;
    int b = idx >> 9, c = idx & 511;
    const float* wp = w + b * 512;
    const float* ap = aw + (size_t)c * 512;
    float s = 0.f;
    #pragma unroll
    for (int i = 0; i < 8; ++i) s += wp[lane + i * 64] * ap[lane + i * 64];
    #pragma unroll
    for (int m = 32; m; m >>= 1) s += __shfl_xor(s, m, 64);
    if (lane == 0) style[idx] = s + ab[c] + 1.0f;
}

// K2: Wb[o][tap][c] = bf16(weight[o][c][tap]); wsq[o][c] = sum_tap w^2
__global__ void k_wprep(const float* __restrict__ weight, ushort* __restrict__ Wb,
                        float* __restrict__ wsq) {
    int t = blockIdx.x * 256 + threadIdx.x;          // 0..262143 = (o,c)
    int o = t >> 9, c = t & 511;
    const float* wp = weight + (size_t)t * 9;
    float sq = 0.f;
    #pragma unroll
    for (int j = 0; j < 9; ++j) {
        float v = wp[j];
        sq += v * v;
        Wb[((size_t)o * 9 + j) * 512 + c] = (ushort)bf16rne(v);
    }
    wsq[t] = sq;
}

// K3: sigma[b][o] = rsqrt( sum_c style^2[b,c] * wsq[o,c] + eps )
__global__ void k_sigma(const float* __restrict__ style, const float* __restrict__ wsq,
                        float* __restrict__ sigma) {
    int idx = blockIdx.x * 4 + (threadIdx.x >> 6);   // (b,o)
    int lane = threadIdx.x & 63;
    int b = idx >> 9, o = idx & 511;
    const float* sp = style + b * 512;
    const float* qp = wsq + (size_t)o * 512;
    float s = 0.f;
    #pragma unroll
    for (int i = 0; i < 8; ++i) {
        float st = sp[lane + i * 64];
        s += st * st * qp[lane + i * 64];
    }
    #pragma unroll
    for (int m = 32; m; m >>= 1) s += __shfl_xor(s, m, 64);
    if (lane == 0) sigma[idx] = rsqrtf(s + 1e-8f);
}

// K4: implicit-GEMM conv. Block: 128 o x 128 px (2 rows of one batch image).
__global__ __launch_bounds__(256, 3) void k_conv(
    const float* __restrict__ x, const ushort* __restrict__ Wb,
    const float* __restrict__ style, const float* __restrict__ sigma,
    const float* __restrict__ bias, float* __restrict__ out) {

    __shared__ ushort sAs[2][128 * 32];   // [buf][o][k] 16B-slot XOR-swizzled
    __shared__ ushort sXt[4 * 66 * 32];   // [row][col][ci] 16B-slot XOR-swizzled

    const int tid = threadIdx.x;
    const int bid = blockIdx.x;
    const int ob = bid & 3;
    const int pb = bid >> 2;              // 0..255
    const int b  = pb >> 5;
    const int y0 = (pb & 31) * 2;
    const int o0 = ob * 128;

    const int wave = tid >> 6;
    const int lane = tid & 63;
    const int l15  = lane & 15;
    const int kg   = lane >> 4;
    const int wr = wave >> 1;             // o sub-tile  (0..1)
    const int wc = wave & 1;              // px sub-tile (0..1) == output row parity

    // xt staging role
    const int sr   = tid >> 6;            // 0..3 source row
    const int scol = tid & 63;            // source col
    const int yy   = y0 - 1 + sr;
    const bool yok = (unsigned)yy < 64u;

    // A staging role
    const int arow  = tid >> 1;           // 0..127
    const int ahalf = tid & 1;
    const int asw   = (arow >> 1) & 3;

    f32x4 acc[4][4];
    #pragma unroll
    for (int i = 0; i < 4; ++i)
        #pragma unroll
        for (int j = 0; j < 4; ++j) acc[i][j] = (f32x4){0.f, 0.f, 0.f, 0.f};

    uint4 rA0, rA1;
    int cb = 0;

    #pragma unroll 1
    for (int cci = 0; cci < 16; ++cci) {
        const int cc = cci * 32;

        // ---- stage x-tile: xt[r][col+1][ci] = bf16(x[b,cc+ci,yy,col]*style) ----
        uint pk[16];
        #pragma unroll
        for (int i = 0; i < 16; ++i) pk[i] = 0;
        if (yok) {
            const float* xp = x + (((size_t)(b * 512 + cc) * 64 + yy) * 64 + scol);
            #pragma unroll
            for (int ci = 0; ci < 32; ++ci) {
                float v = xp[(size_t)ci * 4096] * style[b * 512 + cc + ci];
                pk[ci >> 1] |= bf16rne(v) << ((ci & 1) * 16);
            }
        }
        {
            const int colpos = scol + 1;
            const int xsw = (colpos >> 1) & 3;
            ushort* dst = &sXt[(sr * 66 + colpos) * 32];
            #pragma unroll
            for (int g = 0; g < 4; ++g) {
                *(uint4*)&dst[(g ^ xsw) * 8] =
                    make_uint4(pk[g * 4], pk[g * 4 + 1], pk[g * 4 + 2], pk[g * 4 + 3]);
            }
            uint4 z = make_uint4(0u, 0u, 0u, 0u);
            if (scol == 0) {                       // left zero pad, colpos 0 (xsw=0)
                ushort* d0 = &sXt[(sr * 66 + 0) * 32];
                #pragma unroll
                for (int g = 0; g < 4; ++g) *(uint4*)&d0[g * 8] = z;
            }
            if (scol == 63) {                      // right zero pad, colpos 65 (xsw=0)
                ushort* d1 = &sXt[(sr * 66 + 65) * 32];
                #pragma unroll
                for (int g = 0; g < 4; ++g) *(uint4*)&d1[g * 8] = z;
            }
        }

        // ---- ensure rA holds tap0 of this chunk, commit to sAs[cb] ----
        if (cci == 0) {
            const uint4* p = (const uint4*)(Wb + (((size_t)(o0 + arow) * 9 + 0) * 512 + cc + ahalf * 16));
            rA0 = p[0]; rA1 = p[1];
        }
        {
            ushort* dst = &sAs[cb][arow * 32];
            *(uint4*)&dst[((ahalf * 2 + 0) ^ asw) * 8] = rA0;
            *(uint4*)&dst[((ahalf * 2 + 1) ^ asw) * 8] = rA1;
        }
        __syncthreads();

        #pragma unroll 1
        for (int tap = 0; tap < 9; ++tap) {
            // prefetch next A tile (next tap, or tap0 of next chunk)
            const bool havePref = (tap < 8) || (cci < 15);
            if (havePref) {
                int ptap = (tap < 8) ? tap + 1 : 0;
                int pcc  = (tap < 8) ? cc : cc + 32;
                const uint4* p = (const uint4*)(Wb + (((size_t)(o0 + arow) * 9 + ptap) * 512 + pcc + ahalf * 16));
                rA0 = p[0]; rA1 = p[1];
            }
            const int dy = tap / 3, dx = tap % 3;

            bf16x8 af[4], bfr[4];
            #pragma unroll
            for (int fm = 0; fm < 4; ++fm) {
                int r = wr * 64 + fm * 16 + l15;
                af[fm] = *(const bf16x8*)&sAs[cb][r * 32 + ((kg ^ ((r >> 1) & 3)) * 8)];
            }
            #pragma unroll
            for (int fn = 0; fn < 4; ++fn) {
                int colIdx = fn * 16 + l15 + dx;
                int row = wc + dy;
                bfr[fn] = *(const bf16x8*)&sXt[(row * 66 + colIdx) * 32 + ((kg ^ ((colIdx >> 1) & 3)) * 8)];
            }
            #pragma unroll
            for (int fm = 0; fm < 4; ++fm)
                #pragma unroll
                for (int fn = 0; fn < 4; ++fn)
                    acc[fm][fn] = __builtin_amdgcn_mfma_f32_16x16x32_bf16(af[fm], bfr[fn], acc[fm][fn], 0, 0, 0);

            if (tap < 8) {   // commit prefetched tap+1 into the other buffer
                ushort* dst = &sAs[cb ^ 1][arow * 32];
                *(uint4*)&dst[((ahalf * 2 + 0) ^ asw) * 8] = rA0;
                *(uint4*)&dst[((ahalf * 2 + 1) ^ asw) * 8] = rA1;
            }
            __syncthreads();
            cb ^= 1;
        }
    }

    // ---- epilogue: out = acc * sigma[b,o] + bias[o] ----
    const int yrow = y0 + wc;
    #pragma unroll
    for (int fm = 0; fm < 4; ++fm) {
        #pragma unroll
        for (int j = 0; j < 4; ++j) {
            int o = o0 + wr * 64 + fm * 16 + kg * 4 + j;
            float sg = sigma[b * 512 + o];
            float bs = bias[o];
            float* op = out + (((size_t)(b * 512 + o) * 64 + yrow) * 64);
            #pragma unroll
            for (int fn = 0; fn < 4; ++fn)
                op[fn * 16 + l15] = acc[fm][fn][j] * sg + bs;
        }
    }
}

extern "C" void kernel_launch(void* const* d_in, const int* in_sizes, int n_in,
                              void* d_out, int out_size, void* d_ws, size_t ws_size,
                              hipStream_t stream) {
    const float* x    = (const float*)d_in[0];
    const float* w    = (const float*)d_in[1];
    const float* wt   = (const float*)d_in[2];
    const float* bias = (const float*)d_in[3];
    const float* aw   = (const float*)d_in[4];
    const float* ab   = (const float*)d_in[5];
    float* out = (float*)d_out;

    // workspace layout: style(16KB) | sigma(16KB) | wsq(1MB) | Wb bf16 (4.5MB)
    float* style  = (float*)d_ws;
    float* sigmap = style + 4096;
    float* wsq    = sigmap + 4096;
    ushort* Wb    = (ushort*)(wsq + 512 * 512);

    k_style<<<1024, 256, 0, stream>>>(w, aw, ab, style);
    k_wprep<<<1024, 256, 0, stream>>>(wt, Wb, wsq);
    k_sigma<<<1024, 256, 0, stream>>>(style, wsq, sigmap);
    k_conv <<<1024, 256, 0, stream>>>(x, Wb, style, sigmap, bias, out);
}